// Round 12
// baseline (162.920 us; speedup 1.0000x reference)
//
#include <hip/hip_runtime.h>
#include <hip/hip_bf16.h>

#define NB 32
#define CD 256
#define SS 1024
#define DD 256
#define TT 512
// SCALE * log2(e): softmax computed in base-2
#define QSCALE 0.09016844f

typedef __attribute__((ext_vector_type(8))) short s16x8;
typedef __attribute__((ext_vector_type(4))) short s16x4;
typedef __attribute__((ext_vector_type(4))) float f32x4;
typedef __attribute__((ext_vector_type(16))) float f32x16;
typedef __attribute__((ext_vector_type(4))) unsigned int u32x4;

__device__ __forceinline__ unsigned short f2bf(float f) {
  unsigned u = __builtin_bit_cast(unsigned, f);
  u = (u + 0x7FFFu + ((u >> 16) & 1u)) >> 16;
  return (unsigned short)u;
}
__device__ __forceinline__ float bf2f(unsigned short h) {
  return __builtin_bit_cast(float, ((unsigned)h) << 16);
}
__device__ __forceinline__ unsigned pk2(float a, float b) {
  float2 f2; f2.x = a; f2.y = b;
  __hip_bfloat162 h = __float22bfloat162_rn(f2);
  unsigned u;
  __builtin_memcpy(&u, &h, 4);
  return u;
}
__device__ __forceinline__ float asf(unsigned u) {
  return __builtin_bit_cast(float, u);
}
#define GLOAD16(gp, lp)                                                        \
  __builtin_amdgcn_global_load_lds(                                            \
      (const __attribute__((address_space(1))) unsigned int*)(const void*)(gp),\
      (__attribute__((address_space(3))) unsigned int*)(void*)(lp), 16, 0, 0)

// ---- misc: blocks 0..1023 = weight fp32->bf16; 1024..1055 = temb ----
__global__ __launch_bounds__(256) void k_misc(const float* __restrict__ t,
    const float* __restrict__ Wt, const float* __restrict__ bt, float* __restrict__ temb,
    const float* __restrict__ wq, const float* __restrict__ wk,
    const float* __restrict__ wv, const float* __restrict__ wp,
    unsigned short* __restrict__ dst) {
  const int b = blockIdx.x;
  if (b < 1024) {
    const int i = b * 256 + threadIdx.x;
    const int which = i >> 16, off = i & 65535;
    const float* s = which == 0 ? wq : which == 1 ? wk : which == 2 ? wv : wp;
    dst[i] = f2bf(s[off]);
  } else {
    const int n = b - 1024, c = threadIdx.x;
    const float4* tv = (const float4*)(t + (size_t)n * TT);
    const float4* wvv = (const float4*)(Wt + (size_t)c * TT);
    float acc = 0.f;
#pragma unroll 8
    for (int i = 0; i < TT / 4; ++i) {
      float4 a = tv[i], bb = wvv[i];
      acc += a.x * bb.x + a.y * bb.y + a.z * bb.z + a.w * bb.w;
    }
    acc += bt[c];
    temb[n * CD + c] = fmaxf(acc, 0.f);
  }
}

// ---- xb[n, s, c] = bf16(x[n,c,s] + temb[n,c]) ----
__global__ __launch_bounds__(256) void k_addT(const float* __restrict__ x,
    const float* __restrict__ temb, unsigned short* __restrict__ xb) {
  __shared__ float tile[32][33];
  const int tx = threadIdx.x & 31, ty = threadIdx.x >> 5;
  const int n = blockIdx.z, s0 = blockIdx.y * 32, c0 = blockIdx.x * 32;
#pragma unroll
  for (int i = 0; i < 4; ++i) {
    const int cc = ty + i * 8;
    tile[cc][tx] = x[((size_t)n * CD + c0 + cc) * SS + s0 + tx] + temb[n * CD + c0 + cc];
  }
  __syncthreads();
  unsigned short* op = xb + ((size_t)n * SS + s0) * CD + c0;
#pragma unroll
  for (int i = 0; i < 4; ++i) {
    const int ss = ty + i * 8;
    op[(size_t)ss * CD + tx] = f2bf(tile[tx][ss]);
  }
}

// ---- QKV GEMM, XCD-swizzled 1-D grid (1536): all 48 blocks of one n on one
// XCD so xb_n (512KB) is L2-resident. which==2 writes V transposed. ----
__global__ __launch_bounds__(256) void k_qkv(const unsigned short* __restrict__ A,
    const unsigned short* __restrict__ wb, unsigned short* __restrict__ qb,
    unsigned short* __restrict__ kb, unsigned short* __restrict__ vtb) {
  __shared__ __attribute__((aligned(16))) unsigned short As[128 * 32];
  __shared__ __attribute__((aligned(16))) unsigned short Bs[128 * 32];
  const int bid = blockIdx.x;
  const int xcd = bid & 7, idx = bid >> 3;          // idx 0..191
  const int n = xcd + 8 * (idx / 48);
  const int rem = idx % 48;
  const int which = rem >> 4, tt = rem & 15;
  const int s0 = (tt & 7) * 128;
  const int d0 = (tt >> 3) * 128;
  const unsigned short* B = wb + which * 65536;
  const int tid = threadIdx.x;
  const int lane = tid & 63, wid = tid >> 6;
  const int lo = lane & 15, hi = lane >> 4;
  const int wr = wid >> 1, wc = wid & 1;
  const unsigned short* An = A + (size_t)n * SS * CD;
  f32x4 acc[4][4] = {};
  for (int k0 = 0; k0 < CD; k0 += 32) {
#pragma unroll
    for (int i = 0; i < 2; ++i) {
      const int seg = i * 256 + wid * 64 + lane;
      const int row = seg >> 2, c8 = seg & 3;
      GLOAD16(An + (size_t)(s0 + row) * CD + k0 + c8 * 8, As + (size_t)(i * 256 + wid * 64) * 8);
      GLOAD16(B + (size_t)(d0 + row) * CD + k0 + c8 * 8, Bs + (size_t)(i * 256 + wid * 64) * 8);
    }
    __syncthreads();
    s16x8 a[4], b[4];
#pragma unroll
    for (int mi = 0; mi < 4; ++mi)
      a[mi] = *(const s16x8*)&As[(wr * 64 + mi * 16 + lo) * 32 + hi * 8];
#pragma unroll
    for (int ni = 0; ni < 4; ++ni)
      b[ni] = *(const s16x8*)&Bs[(wc * 64 + ni * 16 + lo) * 32 + hi * 8];
#pragma unroll
    for (int mi = 0; mi < 4; ++mi)
#pragma unroll
      for (int ni = 0; ni < 4; ++ni)
        acc[mi][ni] = __builtin_amdgcn_mfma_f32_16x16x32_bf16(a[mi], b[ni], acc[mi][ni], 0, 0, 0);
    __syncthreads();
  }
  if (which < 2) {
    const float osc = which == 0 ? QSCALE : 1.0f;
    unsigned short* On = (which == 0 ? qb : kb) + (size_t)n * SS * DD;
#pragma unroll
    for (int mi = 0; mi < 4; ++mi) {
      const int r0 = s0 + wr * 64 + mi * 16 + hi * 4;
#pragma unroll
      for (int ni = 0; ni < 4; ++ni) {
        const int col = d0 + wc * 64 + ni * 16 + lo;
#pragma unroll
        for (int r = 0; r < 4; ++r)
          On[(size_t)(r0 + r) * DD + col] = f2bf(acc[mi][ni][r] * osc);
      }
    }
  } else {
    unsigned short* On = vtb + (size_t)n * DD * SS;
#pragma unroll
    for (int mi = 0; mi < 4; ++mi) {
      const int r0 = s0 + wr * 64 + mi * 16 + hi * 4;
#pragma unroll
      for (int ni = 0; ni < 4; ++ni) {
        const int col = d0 + wc * 64 + ni * 16 + lo;
        s16x4 v;
#pragma unroll
        for (int r = 0; r < 4; ++r) v[r] = (short)f2bf(acc[mi][ni][r]);
        *(s16x4*)&On[(size_t)col * SS + r0] = v;
      }
    }
  }
}

// ---- flash attention, swapped 32x32 MFMA, in-register softmax+P (permlane).
// Fixed-max softmax (no running max: scores bounded, fp32/bf16 range safe).
// K in LDS (KVBLK=32, dbuf, XOR-swizzled, 32KB); V^T read DIRECT from global
// (L2-resident via XCD swizzle) as per-lane b128 - no V staging, -1/3 LDS ops.
// grid 512: xcd=bid&7; 4 waves x 32 q-rows; lane owns q=lane&31. ----
__global__ __launch_bounds__(256, 2) void k_attn(const unsigned short* __restrict__ qb,
    const unsigned short* __restrict__ kb, const unsigned short* __restrict__ vtb,
    unsigned short* __restrict__ ob) {
  // ushort elems: Ks[2][8192] => 32KB
  __shared__ __attribute__((aligned(16))) unsigned short lds[16384];
  const int bid = blockIdx.x;
  const int xcd = bid & 7, inner = bid >> 3;
  const int n = xcd + ((inner >> 4) << 3);
  const int sub = inner & 15;
  const int qt = sub & 7, dh = sub >> 3;
  const int tid = threadIdx.x, lane = tid & 63, w = tid >> 6;
  const int l31 = lane & 31, h = lane >> 5;
  const int dblk = dh * 128;
  const unsigned short* Kn = kb + (size_t)n * SS * DD;
  const unsigned short* Vn = vtb + ((size_t)n * DD + dblk) * SS;
  const int qrow = qt * 128 + w * 32 + l31;

  const unsigned short* Qp = qb + ((size_t)n * SS + qrow) * DD + h * 8;
  s16x8 qf[16];
#pragma unroll
  for (int ks = 0; ks < 16; ++ks) qf[ks] = *(const s16x8*)(Qp + ks * 16);

  // per-lane V row bases (loop-invariant): row = dblk + dc*32 + l31
  const unsigned short* Vrow[4];
#pragma unroll
  for (int dc = 0; dc < 4; ++dc) Vrow[dc] = Vn + (size_t)(dc * 32 + l31) * SS;

  f32x16 acc[4] = {};
  float lrun = 0.f;

  auto STAGE_K = [&](int buf, int jt) {
    const int j0 = jt * 32;
    unsigned short* KsB = lds + buf * 8192;
#pragma unroll
    for (int i = 0; i < 4; ++i) {  // K: 32 rows x 256 cols
      const int idx = i * 256 + w * 64 + lane;
      const int row = idx >> 5, c8 = idx & 31;
      GLOAD16(Kn + (size_t)(j0 + row) * DD + ((c8 ^ (row & 7)) << 3),
              KsB + (size_t)(i * 256 + w * 64) * 8);
    }
  };

  STAGE_K(0, 0);
  __syncthreads();

  int cur = 0;
#pragma unroll 1
  for (int jt = 0; jt < 32; ++jt) {
    if (jt + 1 < 32) STAGE_K(cur ^ 1, jt + 1);
    const unsigned short* Ks = lds + cur * 8192;
    const int j0 = jt * 32;
    // ---- QK^T (swapped), 2 independent chains: lane holds S[j=crow(r,h)][q=l31]
    f32x16 sca = {}, scb = {};
    __builtin_amdgcn_s_setprio(1);
#pragma unroll
    for (int ks = 0; ks < 16; ks += 2) {
      const s16x8 kfa = *(const s16x8*)&Ks[l31 * 256 + ((((ks * 2 + h)) ^ (l31 & 7)) << 3)];
      const s16x8 kfb = *(const s16x8*)&Ks[l31 * 256 + (((((ks + 1) * 2 + h)) ^ (l31 & 7)) << 3)];
      sca = __builtin_amdgcn_mfma_f32_32x32x16_bf16(kfa, qf[ks], sca, 0, 0, 0);
      scb = __builtin_amdgcn_mfma_f32_32x32x16_bf16(kfb, qf[ks + 1], scb, 0, 0, 0);
    }
    __builtin_amdgcn_s_setprio(0);
    f32x16 sc = sca + scb;
    // ---- softmax numerator in base-2, fixed max (no tracking) ----
#pragma unroll
    for (int i = 0; i < 16; ++i) sc[i] = exp2f(sc[i]);
    lrun += (((sc[0] + sc[1]) + (sc[2] + sc[3])) + ((sc[4] + sc[5]) + (sc[6] + sc[7]))) +
            (((sc[8] + sc[9]) + (sc[10] + sc[11])) + ((sc[12] + sc[13]) + (sc[14] + sc[15])));
    // ---- P -> A-fragments fully in-register (verified permlane mapping) ----
    const unsigned wv0 = pk2(sc[0], sc[1]),   wv1 = pk2(sc[2], sc[3]);
    const unsigned wv2 = pk2(sc[4], sc[5]),   wv3 = pk2(sc[6], sc[7]);
    const unsigned wv4 = pk2(sc[8], sc[9]),   wv5 = pk2(sc[10], sc[11]);
    const unsigned wv6 = pk2(sc[12], sc[13]), wv7 = pk2(sc[14], sc[15]);
    auto r02 = __builtin_amdgcn_permlane32_swap(wv0, wv2, false, false);
    auto r13 = __builtin_amdgcn_permlane32_swap(wv1, wv3, false, false);
    auto r46 = __builtin_amdgcn_permlane32_swap(wv4, wv6, false, false);
    auto r57 = __builtin_amdgcn_permlane32_swap(wv5, wv7, false, false);
    const u32x4 pa0u = {r02[0], r13[0], r02[1], r13[1]};
    const u32x4 pa1u = {r46[0], r57[0], r46[1], r57[1]};
    const s16x8 pa0 = __builtin_bit_cast(s16x8, pa0u);
    const s16x8 pa1 = __builtin_bit_cast(s16x8, pa1u);
    // ---- PV: V^T fragments per-lane direct from global (L2) ----
    __builtin_amdgcn_s_setprio(1);
#pragma unroll
    for (int dc = 0; dc < 4; ++dc) {
      const s16x8 vf0 = *(const s16x8*)(Vrow[dc] + j0 + h * 8);
      acc[dc] = __builtin_amdgcn_mfma_f32_32x32x16_bf16(vf0, pa0, acc[dc], 0, 0, 0);
    }
#pragma unroll
    for (int dc = 0; dc < 4; ++dc) {
      const s16x8 vf1 = *(const s16x8*)(Vrow[dc] + j0 + 16 + h * 8);
      acc[dc] = __builtin_amdgcn_mfma_f32_32x32x16_bf16(vf1, pa1, acc[dc], 0, 0, 0);
    }
    __builtin_amdgcn_s_setprio(0);
    __syncthreads();  // drains vmcnt(0): next K tile staged; waves past cur
    cur ^= 1;
  }
  {
    auto rl = __builtin_amdgcn_permlane32_swap(__builtin_bit_cast(unsigned, lrun),
                                               __builtin_bit_cast(unsigned, lrun), false, false);
    lrun = asf(rl[0]) + asf(rl[1]);
  }
  const float inv = 1.0f / lrun;
  unsigned short* Op = ob + ((size_t)n * SS + qrow) * DD + dblk;
#pragma unroll
  for (int dc = 0; dc < 4; ++dc)
#pragma unroll
    for (int rg = 0; rg < 4; ++rg) {
      uint2 u;
      u.x = pk2(acc[dc][rg * 4 + 0] * inv, acc[dc][rg * 4 + 1] * inv);
      u.y = pk2(acc[dc][rg * 4 + 2] * inv, acc[dc][rg * 4 + 3] * inv);
      *(uint2*)(Op + dc * 32 + rg * 8 + h * 4) = u;
    }
}

// ---- fused proj + bias + residual, XCD-swizzled 1-D grid (512) ----
__global__ __launch_bounds__(256) void k_proj(const unsigned short* __restrict__ ob,
    const unsigned short* __restrict__ wpb, const float* __restrict__ bp,
    const float* __restrict__ x, float* __restrict__ out) {
  __shared__ __attribute__((aligned(16))) unsigned short As[128 * 32];
  __shared__ __attribute__((aligned(16))) unsigned short Bs[128 * 32];
  const int bid = blockIdx.x;
  const int xcd = bid & 7, idx = bid >> 3;          // idx 0..63
  const int n = xcd + ((idx >> 4) << 3);
  const int rem = idx & 15;
  const int s0 = (rem & 7) * 128;
  const int c0 = (rem >> 3) * 128;
  const int tid = threadIdx.x;
  const int lane = tid & 63, wid = tid >> 6;
  const int lo = lane & 15, hi = lane >> 4;
  const int wr = wid >> 1, wc = wid & 1;
  const unsigned short* On = ob + (size_t)n * SS * DD;
  f32x4 acc[4][4] = {};
  for (int k0 = 0; k0 < DD; k0 += 32) {
#pragma unroll
    for (int i = 0; i < 2; ++i) {
      const int seg = i * 256 + wid * 64 + lane;
      const int row = seg >> 2, c8 = seg & 3;
      GLOAD16(wpb + (size_t)(c0 + row) * DD + k0 + c8 * 8, As + (size_t)(i * 256 + wid * 64) * 8);
      GLOAD16(On + (size_t)(s0 + row) * DD + k0 + c8 * 8, Bs + (size_t)(i * 256 + wid * 64) * 8);
    }
    __syncthreads();
    s16x8 a[4], b[4];
#pragma unroll
    for (int mi = 0; mi < 4; ++mi)
      a[mi] = *(const s16x8*)&As[(wr * 64 + mi * 16 + lo) * 32 + hi * 8];
#pragma unroll
    for (int ni = 0; ni < 4; ++ni)
      b[ni] = *(const s16x8*)&Bs[(wc * 64 + ni * 16 + lo) * 32 + hi * 8];
#pragma unroll
    for (int mi = 0; mi < 4; ++mi)
#pragma unroll
      for (int ni = 0; ni < 4; ++ni)
        acc[mi][ni] = __builtin_amdgcn_mfma_f32_16x16x32_bf16(a[mi], b[ni], acc[mi][ni], 0, 0, 0);
    __syncthreads();
  }
#pragma unroll
  for (int mi = 0; mi < 4; ++mi) {
#pragma unroll
    for (int r = 0; r < 4; ++r) {
      const int c = c0 + wr * 64 + mi * 16 + hi * 4 + r;
      const float bpc = bp[c];
      const size_t base = ((size_t)n * CD + c) * SS;
#pragma unroll
      for (int ni = 0; ni < 4; ++ni) {
        const int s = s0 + wc * 64 + ni * 16 + lo;
        out[base + s] = acc[mi][ni][r] + bpc + x[base + s];
      }
    }
  }
}

extern "C" void kernel_launch(void* const* d_in, const int* in_sizes, int n_in,
                              void* d_out, int out_size, void* d_ws, size_t ws_size,
                              hipStream_t stream) {
  const float* x  = (const float*)d_in[0];
  const float* t  = (const float*)d_in[1];
  const float* Wt = (const float*)d_in[2];
  const float* bt = (const float*)d_in[3];
  const float* Wq = (const float*)d_in[4];
  const float* Wk = (const float*)d_in[5];
  const float* Wv = (const float*)d_in[6];
  const float* Wp = (const float*)d_in[7];
  const float* bp = (const float*)d_in[8];
  char* ws = (char*)d_ws;
  float* temb        = (float*)ws;                              // 32 KB
  unsigned short* wb = (unsigned short*)(ws + 32768);           // 512 KB (q,k,v,p)
  unsigned short* xb = (unsigned short*)(ws + 557056);          // 16 MB [n,s,c]
  unsigned short* qb = (unsigned short*)(ws + 17334272);        // 16 MB [n,s,d]
  unsigned short* kb = (unsigned short*)(ws + 34111488);        // 16 MB [n,s,d]
  unsigned short* vtb = (unsigned short*)(ws + 50888704);       // 16 MB [n,d,s]
  unsigned short* ob = (unsigned short*)(ws + 67665920);        // 16 MB [n,s,d]
  float* out = (float*)d_out;

  k_misc<<<1056, 256, 0, stream>>>(t, Wt, bt, temb, Wq, Wk, Wv, Wp, wb);
  k_addT<<<dim3(8, 32, 32), 256, 0, stream>>>(x, temb, xb);
  k_qkv<<<1536, 256, 0, stream>>>(xb, wb, qb, kb, vtb);
  k_attn<<<512, 256, 0, stream>>>(qb, kb, vtb, ob);
  k_proj<<<512, 256, 0, stream>>>(ob, wb + 196608, bp, x, out);
}

// Round 13
// 142.841 us; speedup vs baseline: 1.1406x; 1.1406x over previous
//
#include <hip/hip_runtime.h>
#include <hip/hip_bf16.h>

#define NB 32
#define CD 256
#define SS 1024
#define DD 256
#define TT 512
// SCALE * log2(e): softmax computed in base-2
#define QSCALE 0.09016844f

typedef __attribute__((ext_vector_type(8))) short s16x8;
typedef __attribute__((ext_vector_type(4))) short s16x4;
typedef __attribute__((ext_vector_type(4))) float f32x4;
typedef __attribute__((ext_vector_type(16))) float f32x16;
typedef __attribute__((ext_vector_type(4))) unsigned int u32x4;

__device__ __forceinline__ unsigned short f2bf(float f) {
  unsigned u = __builtin_bit_cast(unsigned, f);
  u = (u + 0x7FFFu + ((u >> 16) & 1u)) >> 16;
  return (unsigned short)u;
}
__device__ __forceinline__ float bf2f(unsigned short h) {
  return __builtin_bit_cast(float, ((unsigned)h) << 16);
}
__device__ __forceinline__ unsigned pk2(float a, float b) {
  float2 f2; f2.x = a; f2.y = b;
  __hip_bfloat162 h = __float22bfloat162_rn(f2);
  unsigned u;
  __builtin_memcpy(&u, &h, 4);
  return u;
}
__device__ __forceinline__ float asf(unsigned u) {
  return __builtin_bit_cast(float, u);
}
#define GLOAD16(gp, lp)                                                        \
  __builtin_amdgcn_global_load_lds(                                            \
      (const __attribute__((address_space(1))) unsigned int*)(const void*)(gp),\
      (__attribute__((address_space(3))) unsigned int*)(void*)(lp), 16, 0, 0)

// ---- misc: blocks 0..1023 = weight fp32->bf16; 1024..1055 = temb ----
__global__ __launch_bounds__(256) void k_misc(const float* __restrict__ t,
    const float* __restrict__ Wt, const float* __restrict__ bt, float* __restrict__ temb,
    const float* __restrict__ wq, const float* __restrict__ wk,
    const float* __restrict__ wv, const float* __restrict__ wp,
    unsigned short* __restrict__ dst) {
  const int b = blockIdx.x;
  if (b < 1024) {
    const int i = b * 256 + threadIdx.x;
    const int which = i >> 16, off = i & 65535;
    const float* s = which == 0 ? wq : which == 1 ? wk : which == 2 ? wv : wp;
    dst[i] = f2bf(s[off]);
  } else {
    const int n = b - 1024, c = threadIdx.x;
    const float4* tv = (const float4*)(t + (size_t)n * TT);
    const float4* wvv = (const float4*)(Wt + (size_t)c * TT);
    float acc = 0.f;
#pragma unroll 8
    for (int i = 0; i < TT / 4; ++i) {
      float4 a = tv[i], bb = wvv[i];
      acc += a.x * bb.x + a.y * bb.y + a.z * bb.z + a.w * bb.w;
    }
    acc += bt[c];
    temb[n * CD + c] = fmaxf(acc, 0.f);
  }
}

// ---- xb[n, s, c] = bf16(x[n,c,s] + temb[n,c]) ----
__global__ __launch_bounds__(256) void k_addT(const float* __restrict__ x,
    const float* __restrict__ temb, unsigned short* __restrict__ xb) {
  __shared__ float tile[32][33];
  const int tx = threadIdx.x & 31, ty = threadIdx.x >> 5;
  const int n = blockIdx.z, s0 = blockIdx.y * 32, c0 = blockIdx.x * 32;
#pragma unroll
  for (int i = 0; i < 4; ++i) {
    const int cc = ty + i * 8;
    tile[cc][tx] = x[((size_t)n * CD + c0 + cc) * SS + s0 + tx] + temb[n * CD + c0 + cc];
  }
  __syncthreads();
  unsigned short* op = xb + ((size_t)n * SS + s0) * CD + c0;
#pragma unroll
  for (int i = 0; i < 4; ++i) {
    const int ss = ty + i * 8;
    op[(size_t)ss * CD + tx] = f2bf(tile[tx][ss]);
  }
}

// ---- QKV GEMM, XCD-swizzled 1-D grid (1536): all 48 blocks of one n on one
// XCD so xb_n (512KB) is L2-resident. which==2 writes V transposed. ----
__global__ __launch_bounds__(256) void k_qkv(const unsigned short* __restrict__ A,
    const unsigned short* __restrict__ wb, unsigned short* __restrict__ qb,
    unsigned short* __restrict__ kb, unsigned short* __restrict__ vtb) {
  __shared__ __attribute__((aligned(16))) unsigned short As[128 * 32];
  __shared__ __attribute__((aligned(16))) unsigned short Bs[128 * 32];
  const int bid = blockIdx.x;
  const int xcd = bid & 7, idx = bid >> 3;          // idx 0..191
  const int n = xcd + 8 * (idx / 48);
  const int rem = idx % 48;
  const int which = rem >> 4, tt = rem & 15;
  const int s0 = (tt & 7) * 128;
  const int d0 = (tt >> 3) * 128;
  const unsigned short* B = wb + which * 65536;
  const int tid = threadIdx.x;
  const int lane = tid & 63, wid = tid >> 6;
  const int lo = lane & 15, hi = lane >> 4;
  const int wr = wid >> 1, wc = wid & 1;
  const unsigned short* An = A + (size_t)n * SS * CD;
  f32x4 acc[4][4] = {};
  for (int k0 = 0; k0 < CD; k0 += 32) {
#pragma unroll
    for (int i = 0; i < 2; ++i) {
      const int seg = i * 256 + wid * 64 + lane;
      const int row = seg >> 2, c8 = seg & 3;
      GLOAD16(An + (size_t)(s0 + row) * CD + k0 + c8 * 8, As + (size_t)(i * 256 + wid * 64) * 8);
      GLOAD16(B + (size_t)(d0 + row) * CD + k0 + c8 * 8, Bs + (size_t)(i * 256 + wid * 64) * 8);
    }
    __syncthreads();
    s16x8 a[4], b[4];
#pragma unroll
    for (int mi = 0; mi < 4; ++mi)
      a[mi] = *(const s16x8*)&As[(wr * 64 + mi * 16 + lo) * 32 + hi * 8];
#pragma unroll
    for (int ni = 0; ni < 4; ++ni)
      b[ni] = *(const s16x8*)&Bs[(wc * 64 + ni * 16 + lo) * 32 + hi * 8];
#pragma unroll
    for (int mi = 0; mi < 4; ++mi)
#pragma unroll
      for (int ni = 0; ni < 4; ++ni)
        acc[mi][ni] = __builtin_amdgcn_mfma_f32_16x16x32_bf16(a[mi], b[ni], acc[mi][ni], 0, 0, 0);
    __syncthreads();
  }
  if (which < 2) {
    const float osc = which == 0 ? QSCALE : 1.0f;
    unsigned short* On = (which == 0 ? qb : kb) + (size_t)n * SS * DD;
#pragma unroll
    for (int mi = 0; mi < 4; ++mi) {
      const int r0 = s0 + wr * 64 + mi * 16 + hi * 4;
#pragma unroll
      for (int ni = 0; ni < 4; ++ni) {
        const int col = d0 + wc * 64 + ni * 16 + lo;
#pragma unroll
        for (int r = 0; r < 4; ++r)
          On[(size_t)(r0 + r) * DD + col] = f2bf(acc[mi][ni][r] * osc);
      }
    }
  } else {
    unsigned short* On = vtb + (size_t)n * DD * SS;
#pragma unroll
    for (int mi = 0; mi < 4; ++mi) {
      const int r0 = s0 + wr * 64 + mi * 16 + hi * 4;
#pragma unroll
      for (int ni = 0; ni < 4; ++ni) {
        const int col = d0 + wc * 64 + ni * 16 + lo;
        s16x4 v;
#pragma unroll
        for (int r = 0; r < 4; ++r) v[r] = (short)f2bf(acc[mi][ni][r]);
        *(s16x4*)&On[(size_t)col * SS + r0] = v;
      }
    }
  }
}

// ---- flash attention, swapped 32x32 MFMA, in-register softmax+P (permlane).
// Fixed-max base-2 softmax (scores bounded; no running max). grid 512 with
// n->XCD swizzle. 4 waves x 32 q-rows; lane owns q=lane&31. K/V^T dbuf in
// LDS (KVBLK=32, XOR-swizzled, linear dest + pre-swizzled source, 48KB).
// Two independent QK chains. launch_bounds(256,2) = spill-free. ----
__global__ __launch_bounds__(256, 2) void k_attn(const unsigned short* __restrict__ qb,
    const unsigned short* __restrict__ kb, const unsigned short* __restrict__ vtb,
    unsigned short* __restrict__ ob) {
  // ushort elems: Ks[2][8192] @0, Vs[2][4096] @16384  => 48KB
  __shared__ __attribute__((aligned(16))) unsigned short lds[24576];
  const int bid = blockIdx.x;
  const int xcd = bid & 7, inner = bid >> 3;
  const int n = xcd + ((inner >> 4) << 3);
  const int sub = inner & 15;
  const int qt = sub & 7, dh = sub >> 3;
  const int tid = threadIdx.x, lane = tid & 63, w = tid >> 6;
  const int l31 = lane & 31, h = lane >> 5;
  const int dblk = dh * 128;
  const unsigned short* Kn = kb + (size_t)n * SS * DD;
  const unsigned short* Vn = vtb + ((size_t)n * DD + dblk) * SS;
  const int qrow = qt * 128 + w * 32 + l31;

  const unsigned short* Qp = qb + ((size_t)n * SS + qrow) * DD + h * 8;
  s16x8 qf[16];
#pragma unroll
  for (int ks = 0; ks < 16; ++ks) qf[ks] = *(const s16x8*)(Qp + ks * 16);

  f32x16 acc[4] = {};
  float lrun = 0.f;

  auto STAGE = [&](int buf, int jt) {
    const int j0 = jt * 32;
    unsigned short* KsB = lds + buf * 8192;
    unsigned short* VsB = lds + 16384 + buf * 4096;
#pragma unroll
    for (int i = 0; i < 4; ++i) {  // K: 32 rows x 256 cols
      const int idx = i * 256 + w * 64 + lane;
      const int row = idx >> 5, c8 = idx & 31;
      GLOAD16(Kn + (size_t)(j0 + row) * DD + ((c8 ^ (row & 7)) << 3),
              KsB + (size_t)(i * 256 + w * 64) * 8);
    }
#pragma unroll
    for (int i = 0; i < 2; ++i) {  // V^T: 128 d-rows x 32 j-cols
      const int idx = i * 256 + w * 64 + lane;
      const int row = idx >> 2, c8 = idx & 3;
      GLOAD16(Vn + (size_t)row * SS + j0 + ((c8 ^ ((row >> 1) & 3)) << 3),
              VsB + (size_t)(i * 256 + w * 64) * 8);
    }
  };

  STAGE(0, 0);
  __syncthreads();

  int cur = 0;
#pragma unroll 1
  for (int jt = 0; jt < 32; ++jt) {
    if (jt + 1 < 32) STAGE(cur ^ 1, jt + 1);
    const unsigned short* Ks = lds + cur * 8192;
    const unsigned short* Vs = lds + 16384 + cur * 4096;
    // ---- QK^T (swapped), 2 independent chains: lane holds S[j=crow(r,h)][q=l31]
    f32x16 sca = {}, scb = {};
    __builtin_amdgcn_s_setprio(1);
#pragma unroll
    for (int ks = 0; ks < 16; ks += 2) {
      const s16x8 kfa = *(const s16x8*)&Ks[l31 * 256 + ((((ks * 2 + h)) ^ (l31 & 7)) << 3)];
      const s16x8 kfb = *(const s16x8*)&Ks[l31 * 256 + (((((ks + 1) * 2 + h)) ^ (l31 & 7)) << 3)];
      sca = __builtin_amdgcn_mfma_f32_32x32x16_bf16(kfa, qf[ks], sca, 0, 0, 0);
      scb = __builtin_amdgcn_mfma_f32_32x32x16_bf16(kfb, qf[ks + 1], scb, 0, 0, 0);
    }
    __builtin_amdgcn_s_setprio(0);
    f32x16 sc = sca + scb;
    // ---- softmax numerator in base-2, fixed max (no tracking) ----
#pragma unroll
    for (int i = 0; i < 16; ++i) sc[i] = exp2f(sc[i]);
    lrun += (((sc[0] + sc[1]) + (sc[2] + sc[3])) + ((sc[4] + sc[5]) + (sc[6] + sc[7]))) +
            (((sc[8] + sc[9]) + (sc[10] + sc[11])) + ((sc[12] + sc[13]) + (sc[14] + sc[15])));
    // ---- P -> A-fragments fully in-register (verified permlane mapping) ----
    const unsigned wv0 = pk2(sc[0], sc[1]),   wv1 = pk2(sc[2], sc[3]);
    const unsigned wv2 = pk2(sc[4], sc[5]),   wv3 = pk2(sc[6], sc[7]);
    const unsigned wv4 = pk2(sc[8], sc[9]),   wv5 = pk2(sc[10], sc[11]);
    const unsigned wv6 = pk2(sc[12], sc[13]), wv7 = pk2(sc[14], sc[15]);
    auto r02 = __builtin_amdgcn_permlane32_swap(wv0, wv2, false, false);
    auto r13 = __builtin_amdgcn_permlane32_swap(wv1, wv3, false, false);
    auto r46 = __builtin_amdgcn_permlane32_swap(wv4, wv6, false, false);
    auto r57 = __builtin_amdgcn_permlane32_swap(wv5, wv7, false, false);
    const u32x4 pa0u = {r02[0], r13[0], r02[1], r13[1]};
    const u32x4 pa1u = {r46[0], r57[0], r46[1], r57[1]};
    const s16x8 pa0 = __builtin_bit_cast(s16x8, pa0u);
    const s16x8 pa1 = __builtin_bit_cast(s16x8, pa1u);
    // ---- PV from Vs[cur] ----
    __builtin_amdgcn_s_setprio(1);
#pragma unroll
    for (int dc = 0; dc < 4; ++dc) {
      const s16x8 vf0 = *(const s16x8*)&Vs[(dc * 32 + l31) * 32 + ((h ^ ((l31 >> 1) & 3)) << 3)];
      acc[dc] = __builtin_amdgcn_mfma_f32_32x32x16_bf16(vf0, pa0, acc[dc], 0, 0, 0);
    }
#pragma unroll
    for (int dc = 0; dc < 4; ++dc) {
      const s16x8 vf1 = *(const s16x8*)&Vs[(dc * 32 + l31) * 32 + (((2 + h) ^ ((l31 >> 1) & 3)) << 3)];
      acc[dc] = __builtin_amdgcn_mfma_f32_32x32x16_bf16(vf1, pa1, acc[dc], 0, 0, 0);
    }
    __builtin_amdgcn_s_setprio(0);
    __syncthreads();  // drains vmcnt(0): next tile staged; waves past cur
    cur ^= 1;
  }
  {
    auto rl = __builtin_amdgcn_permlane32_swap(__builtin_bit_cast(unsigned, lrun),
                                               __builtin_bit_cast(unsigned, lrun), false, false);
    lrun = asf(rl[0]) + asf(rl[1]);
  }
  const float inv = 1.0f / lrun;
  unsigned short* Op = ob + ((size_t)n * SS + qrow) * DD + dblk;
#pragma unroll
  for (int dc = 0; dc < 4; ++dc)
#pragma unroll
    for (int rg = 0; rg < 4; ++rg) {
      uint2 u;
      u.x = pk2(acc[dc][rg * 4 + 0] * inv, acc[dc][rg * 4 + 1] * inv);
      u.y = pk2(acc[dc][rg * 4 + 2] * inv, acc[dc][rg * 4 + 3] * inv);
      *(uint2*)(Op + dc * 32 + rg * 8 + h * 4) = u;
    }
}

// ---- fused proj + bias + residual, XCD-swizzled 1-D grid (512) ----
__global__ __launch_bounds__(256) void k_proj(const unsigned short* __restrict__ ob,
    const unsigned short* __restrict__ wpb, const float* __restrict__ bp,
    const float* __restrict__ x, float* __restrict__ out) {
  __shared__ __attribute__((aligned(16))) unsigned short As[128 * 32];
  __shared__ __attribute__((aligned(16))) unsigned short Bs[128 * 32];
  const int bid = blockIdx.x;
  const int xcd = bid & 7, idx = bid >> 3;          // idx 0..63
  const int n = xcd + ((idx >> 4) << 3);
  const int rem = idx & 15;
  const int s0 = (rem & 7) * 128;
  const int c0 = (rem >> 3) * 128;
  const int tid = threadIdx.x;
  const int lane = tid & 63, wid = tid >> 6;
  const int lo = lane & 15, hi = lane >> 4;
  const int wr = wid >> 1, wc = wid & 1;
  const unsigned short* On = ob + (size_t)n * SS * DD;
  f32x4 acc[4][4] = {};
  for (int k0 = 0; k0 < DD; k0 += 32) {
#pragma unroll
    for (int i = 0; i < 2; ++i) {
      const int seg = i * 256 + wid * 64 + lane;
      const int row = seg >> 2, c8 = seg & 3;
      GLOAD16(wpb + (size_t)(c0 + row) * DD + k0 + c8 * 8, As + (size_t)(i * 256 + wid * 64) * 8);
      GLOAD16(On + (size_t)(s0 + row) * DD + k0 + c8 * 8, Bs + (size_t)(i * 256 + wid * 64) * 8);
    }
    __syncthreads();
    s16x8 a[4], b[4];
#pragma unroll
    for (int mi = 0; mi < 4; ++mi)
      a[mi] = *(const s16x8*)&As[(wr * 64 + mi * 16 + lo) * 32 + hi * 8];
#pragma unroll
    for (int ni = 0; ni < 4; ++ni)
      b[ni] = *(const s16x8*)&Bs[(wc * 64 + ni * 16 + lo) * 32 + hi * 8];
#pragma unroll
    for (int mi = 0; mi < 4; ++mi)
#pragma unroll
      for (int ni = 0; ni < 4; ++ni)
        acc[mi][ni] = __builtin_amdgcn_mfma_f32_16x16x32_bf16(a[mi], b[ni], acc[mi][ni], 0, 0, 0);
    __syncthreads();
  }
#pragma unroll
  for (int mi = 0; mi < 4; ++mi) {
#pragma unroll
    for (int r = 0; r < 4; ++r) {
      const int c = c0 + wr * 64 + mi * 16 + hi * 4 + r;
      const float bpc = bp[c];
      const size_t base = ((size_t)n * CD + c) * SS;
#pragma unroll
      for (int ni = 0; ni < 4; ++ni) {
        const int s = s0 + wc * 64 + ni * 16 + lo;
        out[base + s] = acc[mi][ni][r] + bpc + x[base + s];
      }
    }
  }
}

extern "C" void kernel_launch(void* const* d_in, const int* in_sizes, int n_in,
                              void* d_out, int out_size, void* d_ws, size_t ws_size,
                              hipStream_t stream) {
  const float* x  = (const float*)d_in[0];
  const float* t  = (const float*)d_in[1];
  const float* Wt = (const float*)d_in[2];
  const float* bt = (const float*)d_in[3];
  const float* Wq = (const float*)d_in[4];
  const float* Wk = (const float*)d_in[5];
  const float* Wv = (const float*)d_in[6];
  const float* Wp = (const float*)d_in[7];
  const float* bp = (const float*)d_in[8];
  char* ws = (char*)d_ws;
  float* temb        = (float*)ws;                              // 32 KB
  unsigned short* wb = (unsigned short*)(ws + 32768);           // 512 KB (q,k,v,p)
  unsigned short* xb = (unsigned short*)(ws + 557056);          // 16 MB [n,s,c]
  unsigned short* qb = (unsigned short*)(ws + 17334272);        // 16 MB [n,s,d]
  unsigned short* kb = (unsigned short*)(ws + 34111488);        // 16 MB [n,s,d]
  unsigned short* vtb = (unsigned short*)(ws + 50888704);       // 16 MB [n,d,s]
  unsigned short* ob = (unsigned short*)(ws + 67665920);        // 16 MB [n,s,d]
  float* out = (float*)d_out;

  k_misc<<<1056, 256, 0, stream>>>(t, Wt, bt, temb, Wq, Wk, Wv, Wp, wb);
  k_addT<<<dim3(8, 32, 32), 256, 0, stream>>>(x, temb, xb);
  k_qkv<<<1536, 256, 0, stream>>>(xb, wb, qb, kb, vtb);
  k_attn<<<512, 256, 0, stream>>>(qb, kb, vtb, ob);
  k_proj<<<512, 256, 0, stream>>>(ob, wb + 196608, bp, x, out);
}

// Round 14
// 136.094 us; speedup vs baseline: 1.1971x; 1.0496x over previous
//
#include <hip/hip_runtime.h>
#include <hip/hip_bf16.h>

#define NB 32
#define CD 256
#define SS 1024
#define DD 256
#define TT 512
// SCALE * log2(e): softmax computed in base-2
#define QSCALE 0.09016844f

typedef __attribute__((ext_vector_type(8))) short s16x8;
typedef __attribute__((ext_vector_type(4))) short s16x4;
typedef __attribute__((ext_vector_type(4))) float f32x4;
typedef __attribute__((ext_vector_type(16))) float f32x16;
typedef __attribute__((ext_vector_type(4))) unsigned int u32x4;

__device__ __forceinline__ unsigned short f2bf(float f) {
  unsigned u = __builtin_bit_cast(unsigned, f);
  u = (u + 0x7FFFu + ((u >> 16) & 1u)) >> 16;
  return (unsigned short)u;
}
__device__ __forceinline__ float bf2f(unsigned short h) {
  return __builtin_bit_cast(float, ((unsigned)h) << 16);
}
__device__ __forceinline__ unsigned pk2(float a, float b) {
  float2 f2; f2.x = a; f2.y = b;
  __hip_bfloat162 h = __float22bfloat162_rn(f2);
  unsigned u;
  __builtin_memcpy(&u, &h, 4);
  return u;
}
__device__ __forceinline__ float asf(unsigned u) {
  return __builtin_bit_cast(float, u);
}
#define GLOAD16(gp, lp)                                                        \
  __builtin_amdgcn_global_load_lds(                                            \
      (const __attribute__((address_space(1))) unsigned int*)(const void*)(gp),\
      (__attribute__((address_space(3))) unsigned int*)(void*)(lp), 16, 0, 0)

// ---- misc: blocks 0..1023 = weight fp32->bf16; 1024..1055 = temb ----
__global__ __launch_bounds__(256) void k_misc(const float* __restrict__ t,
    const float* __restrict__ Wt, const float* __restrict__ bt, float* __restrict__ temb,
    const float* __restrict__ wq, const float* __restrict__ wk,
    const float* __restrict__ wv, const float* __restrict__ wp,
    unsigned short* __restrict__ dst) {
  const int b = blockIdx.x;
  if (b < 1024) {
    const int i = b * 256 + threadIdx.x;
    const int which = i >> 16, off = i & 65535;
    const float* s = which == 0 ? wq : which == 1 ? wk : which == 2 ? wv : wp;
    dst[i] = f2bf(s[off]);
  } else {
    const int n = b - 1024, c = threadIdx.x;
    const float4* tv = (const float4*)(t + (size_t)n * TT);
    const float4* wvv = (const float4*)(Wt + (size_t)c * TT);
    float acc = 0.f;
#pragma unroll 8
    for (int i = 0; i < TT / 4; ++i) {
      float4 a = tv[i], bb = wvv[i];
      acc += a.x * bb.x + a.y * bb.y + a.z * bb.z + a.w * bb.w;
    }
    acc += bt[c];
    temb[n * CD + c] = fmaxf(acc, 0.f);
  }
}

// ---- xb[n, s, c] = bf16(x[n,c,s] + temb[n,c]) ----
__global__ __launch_bounds__(256) void k_addT(const float* __restrict__ x,
    const float* __restrict__ temb, unsigned short* __restrict__ xb) {
  __shared__ float tile[32][33];
  const int tx = threadIdx.x & 31, ty = threadIdx.x >> 5;
  const int n = blockIdx.z, s0 = blockIdx.y * 32, c0 = blockIdx.x * 32;
#pragma unroll
  for (int i = 0; i < 4; ++i) {
    const int cc = ty + i * 8;
    tile[cc][tx] = x[((size_t)n * CD + c0 + cc) * SS + s0 + tx] + temb[n * CD + c0 + cc];
  }
  __syncthreads();
  unsigned short* op = xb + ((size_t)n * SS + s0) * CD + c0;
#pragma unroll
  for (int i = 0; i < 4; ++i) {
    const int ss = ty + i * 8;
    op[(size_t)ss * CD + tx] = f2bf(tile[tx][ss]);
  }
}

// ---- QKV GEMM, XCD-swizzled 1-D grid (1536) ----
__global__ __launch_bounds__(256) void k_qkv(const unsigned short* __restrict__ A,
    const unsigned short* __restrict__ wb, unsigned short* __restrict__ qb,
    unsigned short* __restrict__ kb, unsigned short* __restrict__ vtb) {
  __shared__ __attribute__((aligned(16))) unsigned short As[128 * 32];
  __shared__ __attribute__((aligned(16))) unsigned short Bs[128 * 32];
  const int bid = blockIdx.x;
  const int xcd = bid & 7, idx = bid >> 3;          // idx 0..191
  const int n = xcd + 8 * (idx / 48);
  const int rem = idx % 48;
  const int which = rem >> 4, tt = rem & 15;
  const int s0 = (tt & 7) * 128;
  const int d0 = (tt >> 3) * 128;
  const unsigned short* B = wb + which * 65536;
  const int tid = threadIdx.x;
  const int lane = tid & 63, wid = tid >> 6;
  const int lo = lane & 15, hi = lane >> 4;
  const int wr = wid >> 1, wc = wid & 1;
  const unsigned short* An = A + (size_t)n * SS * CD;
  f32x4 acc[4][4] = {};
  for (int k0 = 0; k0 < CD; k0 += 32) {
#pragma unroll
    for (int i = 0; i < 2; ++i) {
      const int seg = i * 256 + wid * 64 + lane;
      const int row = seg >> 2, c8 = seg & 3;
      GLOAD16(An + (size_t)(s0 + row) * CD + k0 + c8 * 8, As + (size_t)(i * 256 + wid * 64) * 8);
      GLOAD16(B + (size_t)(d0 + row) * CD + k0 + c8 * 8, Bs + (size_t)(i * 256 + wid * 64) * 8);
    }
    __syncthreads();
    s16x8 a[4], b[4];
#pragma unroll
    for (int mi = 0; mi < 4; ++mi)
      a[mi] = *(const s16x8*)&As[(wr * 64 + mi * 16 + lo) * 32 + hi * 8];
#pragma unroll
    for (int ni = 0; ni < 4; ++ni)
      b[ni] = *(const s16x8*)&Bs[(wc * 64 + ni * 16 + lo) * 32 + hi * 8];
#pragma unroll
    for (int mi = 0; mi < 4; ++mi)
#pragma unroll
      for (int ni = 0; ni < 4; ++ni)
        acc[mi][ni] = __builtin_amdgcn_mfma_f32_16x16x32_bf16(a[mi], b[ni], acc[mi][ni], 0, 0, 0);
    __syncthreads();
  }
  if (which < 2) {
    const float osc = which == 0 ? QSCALE : 1.0f;
    unsigned short* On = (which == 0 ? qb : kb) + (size_t)n * SS * DD;
#pragma unroll
    for (int mi = 0; mi < 4; ++mi) {
      const int r0 = s0 + wr * 64 + mi * 16 + hi * 4;
#pragma unroll
      for (int ni = 0; ni < 4; ++ni) {
        const int col = d0 + wc * 64 + ni * 16 + lo;
#pragma unroll
        for (int r = 0; r < 4; ++r)
          On[(size_t)(r0 + r) * DD + col] = f2bf(acc[mi][ni][r] * osc);
      }
    }
  } else {
    unsigned short* On = vtb + (size_t)n * DD * SS;
#pragma unroll
    for (int mi = 0; mi < 4; ++mi) {
      const int r0 = s0 + wr * 64 + mi * 16 + hi * 4;
#pragma unroll
      for (int ni = 0; ni < 4; ++ni) {
        const int col = d0 + wc * 64 + ni * 16 + lo;
        s16x4 v;
#pragma unroll
        for (int r = 0; r < 4; ++r) v[r] = (short)f2bf(acc[mi][ni][r]);
        *(s16x4*)&On[(size_t)col * SS + r0] = v;
      }
    }
  }
}

// ---- flash attention, swapped 32x32 MFMA, fixed-max base-2 softmax,
// in-register P (permlane). Depth-2 software pipeline: QK(t+1) overlaps
// softmax(t)+PV(t); K/V TRIPLE-buffered (72KB LDS) so staging never
// overwrites a live buffer (deposit target last read 2 barriers ago).
// grid 512 w/ n->XCD swizzle; 4 waves x 32 q-rows; lane owns q=lane&31. ----
__global__ __launch_bounds__(256, 2) void k_attn(const unsigned short* __restrict__ qb,
    const unsigned short* __restrict__ kb, const unsigned short* __restrict__ vtb,
    unsigned short* __restrict__ ob) {
  // ushort elems: K[3][8192] @0 (48KB), V[3][4096] @24576 (24KB) => 72KB
  __shared__ __attribute__((aligned(16))) unsigned short lds[36864];
  const int bid = blockIdx.x;
  const int xcd = bid & 7, inner = bid >> 3;
  const int n = xcd + ((inner >> 4) << 3);
  const int sub = inner & 15;
  const int qt = sub & 7, dh = sub >> 3;
  const int tid = threadIdx.x, lane = tid & 63, w = tid >> 6;
  const int l31 = lane & 31, h = lane >> 5;
  const int dblk = dh * 128;
  const unsigned short* Kn = kb + (size_t)n * SS * DD;
  const unsigned short* Vn = vtb + ((size_t)n * DD + dblk) * SS;
  const int qrow = qt * 128 + w * 32 + l31;

  const unsigned short* Qp = qb + ((size_t)n * SS + qrow) * DD + h * 8;
  s16x8 qf[16];
#pragma unroll
  for (int ks = 0; ks < 16; ++ks) qf[ks] = *(const s16x8*)(Qp + ks * 16);

  f32x16 acc[4] = {};
  float lrun = 0.f;

  auto STAGE = [&](int buf, int jt) {
    const int j0 = jt * 32;
    unsigned short* KsB = lds + buf * 8192;
    unsigned short* VsB = lds + 24576 + buf * 4096;
#pragma unroll
    for (int i = 0; i < 4; ++i) {  // K: 32 rows x 256 cols
      const int idx = i * 256 + w * 64 + lane;
      const int row = idx >> 5, c8 = idx & 31;
      GLOAD16(Kn + (size_t)(j0 + row) * DD + ((c8 ^ (row & 7)) << 3),
              KsB + (size_t)(i * 256 + w * 64) * 8);
    }
#pragma unroll
    for (int i = 0; i < 2; ++i) {  // V^T: 128 d-rows x 32 j-cols
      const int idx = i * 256 + w * 64 + lane;
      const int row = idx >> 2, c8 = idx & 3;
      GLOAD16(Vn + (size_t)row * SS + j0 + ((c8 ^ ((row >> 1) & 3)) << 3),
              VsB + (size_t)(i * 256 + w * 64) * 8);
    }
  };

  STAGE(0, 0);
  STAGE(1, 1);
  __syncthreads();

  // prologue: scores for tile 0
  f32x16 scc = {};
#pragma unroll
  for (int ks = 0; ks < 16; ++ks) {
    const s16x8 kf = *(const s16x8*)&lds[l31 * 256 + ((((ks * 2 + h)) ^ (l31 & 7)) << 3)];
    scc = __builtin_amdgcn_mfma_f32_32x32x16_bf16(kf, qf[ks], scc, 0, 0, 0);
  }

  int sb = 2, qkb = 1, pvb = 0;  // stage / qk-next / pv buffer rotation
#pragma unroll 1
  for (int t = 0; t < 32; ++t) {
    if (t + 2 < 32) STAGE(sb, t + 2);
    // ---- QK^T for tile t+1 (independent: overlaps softmax+PV below) ----
    f32x16 scn = {};
    if (t + 1 < 32) {
      const unsigned short* Ks = lds + qkb * 8192;
      __builtin_amdgcn_s_setprio(1);
#pragma unroll
      for (int ks = 0; ks < 16; ++ks) {
        const s16x8 kf = *(const s16x8*)&Ks[l31 * 256 + ((((ks * 2 + h)) ^ (l31 & 7)) << 3)];
        scn = __builtin_amdgcn_mfma_f32_32x32x16_bf16(kf, qf[ks], scn, 0, 0, 0);
      }
      __builtin_amdgcn_s_setprio(0);
    }
    // ---- softmax(t): numerator in base-2, fixed max ----
#pragma unroll
    for (int i = 0; i < 16; ++i) scc[i] = __builtin_amdgcn_exp2f(scc[i]);
    lrun += (((scc[0] + scc[1]) + (scc[2] + scc[3])) + ((scc[4] + scc[5]) + (scc[6] + scc[7]))) +
            (((scc[8] + scc[9]) + (scc[10] + scc[11])) + ((scc[12] + scc[13]) + (scc[14] + scc[15])));
    // ---- P -> A-fragments in-register (verified permlane mapping) ----
    const unsigned wv0 = pk2(scc[0], scc[1]),   wv1 = pk2(scc[2], scc[3]);
    const unsigned wv2 = pk2(scc[4], scc[5]),   wv3 = pk2(scc[6], scc[7]);
    const unsigned wv4 = pk2(scc[8], scc[9]),   wv5 = pk2(scc[10], scc[11]);
    const unsigned wv6 = pk2(scc[12], scc[13]), wv7 = pk2(scc[14], scc[15]);
    auto r02 = __builtin_amdgcn_permlane32_swap(wv0, wv2, false, false);
    auto r13 = __builtin_amdgcn_permlane32_swap(wv1, wv3, false, false);
    auto r46 = __builtin_amdgcn_permlane32_swap(wv4, wv6, false, false);
    auto r57 = __builtin_amdgcn_permlane32_swap(wv5, wv7, false, false);
    const u32x4 pa0u = {r02[0], r13[0], r02[1], r13[1]};
    const u32x4 pa1u = {r46[0], r57[0], r46[1], r57[1]};
    const s16x8 pa0 = __builtin_bit_cast(s16x8, pa0u);
    const s16x8 pa1 = __builtin_bit_cast(s16x8, pa1u);
    // ---- PV(t) from V[pvb] ----
    const unsigned short* Vs = lds + 24576 + pvb * 4096;
    __builtin_amdgcn_s_setprio(1);
#pragma unroll
    for (int dc = 0; dc < 4; ++dc) {
      const s16x8 vf0 = *(const s16x8*)&Vs[(dc * 32 + l31) * 32 + ((h ^ ((l31 >> 1) & 3)) << 3)];
      acc[dc] = __builtin_amdgcn_mfma_f32_32x32x16_bf16(vf0, pa0, acc[dc], 0, 0, 0);
    }
#pragma unroll
    for (int dc = 0; dc < 4; ++dc) {
      const s16x8 vf1 = *(const s16x8*)&Vs[(dc * 32 + l31) * 32 + (((2 + h) ^ ((l31 >> 1) & 3)) << 3)];
      acc[dc] = __builtin_amdgcn_mfma_f32_32x32x16_bf16(vf1, pa1, acc[dc], 0, 0, 0);
    }
    __builtin_amdgcn_s_setprio(0);
    __syncthreads();  // drains this wave's staging vmcnt; all waves past V[pvb]
    scc = scn;
    sb = (sb + 1 == 3) ? 0 : sb + 1;
    qkb = (qkb + 1 == 3) ? 0 : qkb + 1;
    pvb = (pvb + 1 == 3) ? 0 : pvb + 1;
  }
  {
    auto rl = __builtin_amdgcn_permlane32_swap(__builtin_bit_cast(unsigned, lrun),
                                               __builtin_bit_cast(unsigned, lrun), false, false);
    lrun = asf(rl[0]) + asf(rl[1]);
  }
  const float inv = 1.0f / lrun;
  unsigned short* Op = ob + ((size_t)n * SS + qrow) * DD + dblk;
#pragma unroll
  for (int dc = 0; dc < 4; ++dc)
#pragma unroll
    for (int rg = 0; rg < 4; ++rg) {
      uint2 u;
      u.x = pk2(acc[dc][rg * 4 + 0] * inv, acc[dc][rg * 4 + 1] * inv);
      u.y = pk2(acc[dc][rg * 4 + 2] * inv, acc[dc][rg * 4 + 3] * inv);
      *(uint2*)(Op + dc * 32 + rg * 8 + h * 4) = u;
    }
}

// ---- fused proj + bias + residual, XCD-swizzled 1-D grid (512) ----
__global__ __launch_bounds__(256) void k_proj(const unsigned short* __restrict__ ob,
    const unsigned short* __restrict__ wpb, const float* __restrict__ bp,
    const float* __restrict__ x, float* __restrict__ out) {
  __shared__ __attribute__((aligned(16))) unsigned short As[128 * 32];
  __shared__ __attribute__((aligned(16))) unsigned short Bs[128 * 32];
  const int bid = blockIdx.x;
  const int xcd = bid & 7, idx = bid >> 3;          // idx 0..63
  const int n = xcd + ((idx >> 4) << 3);
  const int rem = idx & 15;
  const int s0 = (rem & 7) * 128;
  const int c0 = (rem >> 3) * 128;
  const int tid = threadIdx.x;
  const int lane = tid & 63, wid = tid >> 6;
  const int lo = lane & 15, hi = lane >> 4;
  const int wr = wid >> 1, wc = wid & 1;
  const unsigned short* On = ob + (size_t)n * SS * DD;
  f32x4 acc[4][4] = {};
  for (int k0 = 0; k0 < DD; k0 += 32) {
#pragma unroll
    for (int i = 0; i < 2; ++i) {
      const int seg = i * 256 + wid * 64 + lane;
      const int row = seg >> 2, c8 = seg & 3;
      GLOAD16(wpb + (size_t)(c0 + row) * DD + k0 + c8 * 8, As + (size_t)(i * 256 + wid * 64) * 8);
      GLOAD16(On + (size_t)(s0 + row) * DD + k0 + c8 * 8, Bs + (size_t)(i * 256 + wid * 64) * 8);
    }
    __syncthreads();
    s16x8 a[4], b[4];
#pragma unroll
    for (int mi = 0; mi < 4; ++mi)
      a[mi] = *(const s16x8*)&As[(wr * 64 + mi * 16 + lo) * 32 + hi * 8];
#pragma unroll
    for (int ni = 0; ni < 4; ++ni)
      b[ni] = *(const s16x8*)&Bs[(wc * 64 + ni * 16 + lo) * 32 + hi * 8];
#pragma unroll
    for (int mi = 0; mi < 4; ++mi)
#pragma unroll
      for (int ni = 0; ni < 4; ++ni)
        acc[mi][ni] = __builtin_amdgcn_mfma_f32_16x16x32_bf16(a[mi], b[ni], acc[mi][ni], 0, 0, 0);
    __syncthreads();
  }
#pragma unroll
  for (int mi = 0; mi < 4; ++mi) {
#pragma unroll
    for (int r = 0; r < 4; ++r) {
      const int c = c0 + wr * 64 + mi * 16 + hi * 4 + r;
      const float bpc = bp[c];
      const size_t base = ((size_t)n * CD + c) * SS;
#pragma unroll
      for (int ni = 0; ni < 4; ++ni) {
        const int s = s0 + wc * 64 + ni * 16 + lo;
        out[base + s] = acc[mi][ni][r] + bpc + x[base + s];
      }
    }
  }
}

extern "C" void kernel_launch(void* const* d_in, const int* in_sizes, int n_in,
                              void* d_out, int out_size, void* d_ws, size_t ws_size,
                              hipStream_t stream) {
  const float* x  = (const float*)d_in[0];
  const float* t  = (const float*)d_in[1];
  const float* Wt = (const float*)d_in[2];
  const float* bt = (const float*)d_in[3];
  const float* Wq = (const float*)d_in[4];
  const float* Wk = (const float*)d_in[5];
  const float* Wv = (const float*)d_in[6];
  const float* Wp = (const float*)d_in[7];
  const float* bp = (const float*)d_in[8];
  char* ws = (char*)d_ws;
  float* temb        = (float*)ws;                              // 32 KB
  unsigned short* wb = (unsigned short*)(ws + 32768);           // 512 KB (q,k,v,p)
  unsigned short* xb = (unsigned short*)(ws + 557056);          // 16 MB [n,s,c]
  unsigned short* qb = (unsigned short*)(ws + 17334272);        // 16 MB [n,s,d]
  unsigned short* kb = (unsigned short*)(ws + 34111488);        // 16 MB [n,s,d]
  unsigned short* vtb = (unsigned short*)(ws + 50888704);       // 16 MB [n,d,s]
  unsigned short* ob = (unsigned short*)(ws + 67665920);        // 16 MB [n,s,d]
  float* out = (float*)d_out;

  k_misc<<<1056, 256, 0, stream>>>(t, Wt, bt, temb, Wq, Wk, Wv, Wp, wb);
  k_addT<<<dim3(8, 32, 32), 256, 0, stream>>>(x, temb, xb);
  k_qkv<<<1536, 256, 0, stream>>>(xb, wb, qb, kb, vtb);
  k_attn<<<512, 256, 0, stream>>>(qb, kb, vtb, ob);
  k_proj<<<512, 256, 0, stream>>>(ob, wb + 196608, bp, x, out);
}

// Round 15
// 133.686 us; speedup vs baseline: 1.2187x; 1.0180x over previous
//
#include <hip/hip_runtime.h>
#include <hip/hip_bf16.h>

#define NB 32
#define CD 256
#define SS 1024
#define DD 256
#define TT 512
// sqrt(SCALE * log2(e)) folded into BOTH Q and K (fp8-friendly magnitudes)
#define OSC8 0.30028060f

typedef __attribute__((ext_vector_type(8))) short s16x8;
typedef __attribute__((ext_vector_type(4))) short s16x4;
typedef __attribute__((ext_vector_type(4))) float f32x4;
typedef __attribute__((ext_vector_type(16))) float f32x16;
typedef __attribute__((ext_vector_type(4))) unsigned int u32x4;

__device__ __forceinline__ unsigned short f2bf(float f) {
  unsigned u = __builtin_bit_cast(unsigned, f);
  u = (u + 0x7FFFu + ((u >> 16) & 1u)) >> 16;
  return (unsigned short)u;
}
__device__ __forceinline__ float bf2f(unsigned short h) {
  return __builtin_bit_cast(float, ((unsigned)h) << 16);
}
__device__ __forceinline__ unsigned pk2(float a, float b) {
  float2 f2; f2.x = a; f2.y = b;
  __hip_bfloat162 h = __float22bfloat162_rn(f2);
  unsigned u;
  __builtin_memcpy(&u, &h, 4);
  return u;
}
__device__ __forceinline__ float asf(unsigned u) {
  return __builtin_bit_cast(float, u);
}
__device__ __forceinline__ unsigned char f2fp8(float v) {
  int p = __builtin_amdgcn_cvt_pk_fp8_f32(v, v, 0, false);
  return (unsigned char)(p & 0xFF);
}
#define GLOAD16(gp, lp)                                                        \
  __builtin_amdgcn_global_load_lds(                                            \
      (const __attribute__((address_space(1))) unsigned int*)(const void*)(gp),\
      (__attribute__((address_space(3))) unsigned int*)(void*)(lp), 16, 0, 0)

// ---- misc: blocks 0..1023 = weight fp32->bf16; 1024..1055 = temb ----
__global__ __launch_bounds__(256) void k_misc(const float* __restrict__ t,
    const float* __restrict__ Wt, const float* __restrict__ bt, float* __restrict__ temb,
    const float* __restrict__ wq, const float* __restrict__ wk,
    const float* __restrict__ wv, const float* __restrict__ wp,
    unsigned short* __restrict__ dst) {
  const int b = blockIdx.x;
  if (b < 1024) {
    const int i = b * 256 + threadIdx.x;
    const int which = i >> 16, off = i & 65535;
    const float* s = which == 0 ? wq : which == 1 ? wk : which == 2 ? wv : wp;
    dst[i] = f2bf(s[off]);
  } else {
    const int n = b - 1024, c = threadIdx.x;
    const float4* tv = (const float4*)(t + (size_t)n * TT);
    const float4* wvv = (const float4*)(Wt + (size_t)c * TT);
    float acc = 0.f;
#pragma unroll 8
    for (int i = 0; i < TT / 4; ++i) {
      float4 a = tv[i], bb = wvv[i];
      acc += a.x * bb.x + a.y * bb.y + a.z * bb.z + a.w * bb.w;
    }
    acc += bt[c];
    temb[n * CD + c] = fmaxf(acc, 0.f);
  }
}

// ---- xb[n, s, c] = bf16(x[n,c,s] + temb[n,c]) ----
__global__ __launch_bounds__(256) void k_addT(const float* __restrict__ x,
    const float* __restrict__ temb, unsigned short* __restrict__ xb) {
  __shared__ float tile[32][33];
  const int tx = threadIdx.x & 31, ty = threadIdx.x >> 5;
  const int n = blockIdx.z, s0 = blockIdx.y * 32, c0 = blockIdx.x * 32;
#pragma unroll
  for (int i = 0; i < 4; ++i) {
    const int cc = ty + i * 8;
    tile[cc][tx] = x[((size_t)n * CD + c0 + cc) * SS + s0 + tx] + temb[n * CD + c0 + cc];
  }
  __syncthreads();
  unsigned short* op = xb + ((size_t)n * SS + s0) * CD + c0;
#pragma unroll
  for (int i = 0; i < 4; ++i) {
    const int ss = ty + i * 8;
    op[(size_t)ss * CD + tx] = f2bf(tile[tx][ss]);
  }
}

// ---- QKV GEMM, XCD-swizzled. which<2 -> fp8 (Q,K scaled by OSC8);
//      which==2 -> V transposed bf16. ----
__global__ __launch_bounds__(256) void k_qkv(const unsigned short* __restrict__ A,
    const unsigned short* __restrict__ wb, unsigned char* __restrict__ qb8,
    unsigned char* __restrict__ kb8, unsigned short* __restrict__ vtb) {
  __shared__ __attribute__((aligned(16))) unsigned short As[128 * 32];
  __shared__ __attribute__((aligned(16))) unsigned short Bs[128 * 32];
  const int bid = blockIdx.x;
  const int xcd = bid & 7, idx = bid >> 3;          // idx 0..191
  const int n = xcd + 8 * (idx / 48);
  const int rem = idx % 48;
  const int which = rem >> 4, tt = rem & 15;
  const int s0 = (tt & 7) * 128;
  const int d0 = (tt >> 3) * 128;
  const unsigned short* B = wb + which * 65536;
  const int tid = threadIdx.x;
  const int lane = tid & 63, wid = tid >> 6;
  const int lo = lane & 15, hi = lane >> 4;
  const int wr = wid >> 1, wc = wid & 1;
  const unsigned short* An = A + (size_t)n * SS * CD;
  f32x4 acc[4][4] = {};
  for (int k0 = 0; k0 < CD; k0 += 32) {
#pragma unroll
    for (int i = 0; i < 2; ++i) {
      const int seg = i * 256 + wid * 64 + lane;
      const int row = seg >> 2, c8 = seg & 3;
      GLOAD16(An + (size_t)(s0 + row) * CD + k0 + c8 * 8, As + (size_t)(i * 256 + wid * 64) * 8);
      GLOAD16(B + (size_t)(d0 + row) * CD + k0 + c8 * 8, Bs + (size_t)(i * 256 + wid * 64) * 8);
    }
    __syncthreads();
    s16x8 a[4], b[4];
#pragma unroll
    for (int mi = 0; mi < 4; ++mi)
      a[mi] = *(const s16x8*)&As[(wr * 64 + mi * 16 + lo) * 32 + hi * 8];
#pragma unroll
    for (int ni = 0; ni < 4; ++ni)
      b[ni] = *(const s16x8*)&Bs[(wc * 64 + ni * 16 + lo) * 32 + hi * 8];
#pragma unroll
    for (int mi = 0; mi < 4; ++mi)
#pragma unroll
      for (int ni = 0; ni < 4; ++ni)
        acc[mi][ni] = __builtin_amdgcn_mfma_f32_16x16x32_bf16(a[mi], b[ni], acc[mi][ni], 0, 0, 0);
    __syncthreads();
  }
  if (which < 2) {
    unsigned char* On = (which == 0 ? qb8 : kb8) + (size_t)n * SS * DD;
#pragma unroll
    for (int mi = 0; mi < 4; ++mi) {
      const int r0 = s0 + wr * 64 + mi * 16 + hi * 4;
#pragma unroll
      for (int ni = 0; ni < 4; ++ni) {
        const int col = d0 + wc * 64 + ni * 16 + lo;
#pragma unroll
        for (int r = 0; r < 4; ++r)
          On[(size_t)(r0 + r) * DD + col] = f2fp8(acc[mi][ni][r] * OSC8);
      }
    }
  } else {
    unsigned short* On = vtb + (size_t)n * DD * SS;
#pragma unroll
    for (int mi = 0; mi < 4; ++mi) {
      const int r0 = s0 + wr * 64 + mi * 16 + hi * 4;
#pragma unroll
      for (int ni = 0; ni < 4; ++ni) {
        const int col = d0 + wc * 64 + ni * 16 + lo;
        s16x4 v;
#pragma unroll
        for (int r = 0; r < 4; ++r) v[r] = (short)f2bf(acc[mi][ni][r]);
        *(s16x4*)&On[(size_t)col * SS + r0] = v;
      }
    }
  }
}

// ---- flash attention: QK^T in fp8 (32x32x16_fp8_fp8, b64 K-frag reads),
// PV in bf16 (unchanged verified path). Fixed-max base-2 softmax, in-register
// P (pk2+permlane). Depth-2 pipeline, K/V triple-buffered (48KB LDS).
// grid 512 w/ n->XCD swizzle; 4 waves x 32 q-rows; lane owns q=lane&31. ----
__global__ __launch_bounds__(256, 2) void k_attn(const unsigned char* __restrict__ qb8,
    const unsigned char* __restrict__ kb8, const unsigned short* __restrict__ vtb,
    unsigned short* __restrict__ ob) {
  // bytes: K[3][8192] @0 (24KB fp8), V[3][8192] @24576 (24KB bf16) => 48KB
  __shared__ __attribute__((aligned(16))) unsigned short lds[24576];
  const int bid = blockIdx.x;
  const int xcd = bid & 7, inner = bid >> 3;
  const int n = xcd + ((inner >> 4) << 3);
  const int sub = inner & 15;
  const int qt = sub & 7, dh = sub >> 3;
  const int tid = threadIdx.x, lane = tid & 63, w = tid >> 6;
  const int l31 = lane & 31, h = lane >> 5;
  const int dblk = dh * 128;
  const unsigned char* Kn8 = kb8 + (size_t)n * SS * DD;
  const unsigned short* Vn = vtb + ((size_t)n * DD + dblk) * SS;
  const int qrow = qt * 128 + w * 32 + l31;

  // Q fragments fp8: lane holds Q[q=qrow][k = ks*16 + h*8 + e], 8 bytes
  const unsigned char* Qp8 = qb8 + ((size_t)n * SS + qrow) * DD + h * 8;
  long qf8[16];
#pragma unroll
  for (int ks = 0; ks < 16; ++ks) qf8[ks] = *(const long*)(Qp8 + ks * 16);

  f32x16 acc[4] = {};
  float lrun = 0.f;

  auto STAGE = [&](int buf, int jt) {
    const int j0 = jt * 32;
    unsigned char* KsB = (unsigned char*)lds + buf * 8192;
    unsigned char* VsB = (unsigned char*)lds + 24576 + buf * 8192;
#pragma unroll
    for (int i = 0; i < 2; ++i) {  // K fp8: 32 rows x 256B (8KB)
      const int id = i * 256 + w * 64 + lane;
      const int row = id >> 4, p = id & 15;
      GLOAD16(Kn8 + (size_t)(j0 + row) * DD + ((p ^ (row & 7)) << 4),
              KsB + (size_t)(i * 256 + w * 64) * 16);
    }
#pragma unroll
    for (int i = 0; i < 2; ++i) {  // V^T bf16: 128 d-rows x 32 j-cols (8KB)
      const int id = i * 256 + w * 64 + lane;
      const int row = id >> 2, c8 = id & 3;
      GLOAD16(Vn + (size_t)row * SS + j0 + ((c8 ^ ((row >> 1) & 3)) << 3),
              VsB + (size_t)(i * 256 + w * 64) * 16);
    }
  };

  STAGE(0, 0);
  STAGE(1, 1);
  __syncthreads();

  // prologue: scores for tile 0 (fp8 QK^T; lane holds S[j=crow(r,h)][q=l31])
  f32x16 scc = {};
  {
    const unsigned char* Ks = (const unsigned char*)lds;
#pragma unroll
    for (int ks = 0; ks < 16; ++ks) {
      const long kf = *(const long*)(Ks + l31 * 256 + ((ks ^ (l31 & 7)) << 4) + h * 8);
      scc = __builtin_amdgcn_mfma_f32_32x32x16_fp8_fp8(kf, qf8[ks], scc, 0, 0, 0);
    }
  }

  int sb = 2, qkb = 1, pvb = 0;  // stage / qk-next / pv buffer rotation
#pragma unroll 1
  for (int t = 0; t < 32; ++t) {
    if (t + 2 < 32) STAGE(sb, t + 2);
    // ---- QK^T for tile t+1 (fp8; overlaps softmax+PV below) ----
    f32x16 scn = {};
    if (t + 1 < 32) {
      const unsigned char* Ks = (const unsigned char*)lds + qkb * 8192;
      __builtin_amdgcn_s_setprio(1);
#pragma unroll
      for (int ks = 0; ks < 16; ++ks) {
        const long kf = *(const long*)(Ks + l31 * 256 + ((ks ^ (l31 & 7)) << 4) + h * 8);
        scn = __builtin_amdgcn_mfma_f32_32x32x16_fp8_fp8(kf, qf8[ks], scn, 0, 0, 0);
      }
      __builtin_amdgcn_s_setprio(0);
    }
    // ---- softmax(t): numerator in base-2, fixed max ----
#pragma unroll
    for (int i = 0; i < 16; ++i) scc[i] = __builtin_amdgcn_exp2f(scc[i]);
    lrun += (((scc[0] + scc[1]) + (scc[2] + scc[3])) + ((scc[4] + scc[5]) + (scc[6] + scc[7]))) +
            (((scc[8] + scc[9]) + (scc[10] + scc[11])) + ((scc[12] + scc[13]) + (scc[14] + scc[15])));
    // ---- P -> bf16 A-fragments in-register (verified permlane mapping) ----
    const unsigned wv0 = pk2(scc[0], scc[1]),   wv1 = pk2(scc[2], scc[3]);
    const unsigned wv2 = pk2(scc[4], scc[5]),   wv3 = pk2(scc[6], scc[7]);
    const unsigned wv4 = pk2(scc[8], scc[9]),   wv5 = pk2(scc[10], scc[11]);
    const unsigned wv6 = pk2(scc[12], scc[13]), wv7 = pk2(scc[14], scc[15]);
    auto r02 = __builtin_amdgcn_permlane32_swap(wv0, wv2, false, false);
    auto r13 = __builtin_amdgcn_permlane32_swap(wv1, wv3, false, false);
    auto r46 = __builtin_amdgcn_permlane32_swap(wv4, wv6, false, false);
    auto r57 = __builtin_amdgcn_permlane32_swap(wv5, wv7, false, false);
    const u32x4 pa0u = {r02[0], r13[0], r02[1], r13[1]};
    const u32x4 pa1u = {r46[0], r57[0], r46[1], r57[1]};
    const s16x8 pa0 = __builtin_bit_cast(s16x8, pa0u);
    const s16x8 pa1 = __builtin_bit_cast(s16x8, pa1u);
    // ---- PV(t) bf16 from V[pvb] ----
    const unsigned short* Vs = (const unsigned short*)((const unsigned char*)lds + 24576 + pvb * 8192);
    __builtin_amdgcn_s_setprio(1);
#pragma unroll
    for (int dc = 0; dc < 4; ++dc) {
      const s16x8 vf0 = *(const s16x8*)&Vs[(dc * 32 + l31) * 32 + ((h ^ ((l31 >> 1) & 3)) << 3)];
      acc[dc] = __builtin_amdgcn_mfma_f32_32x32x16_bf16(vf0, pa0, acc[dc], 0, 0, 0);
    }
#pragma unroll
    for (int dc = 0; dc < 4; ++dc) {
      const s16x8 vf1 = *(const s16x8*)&Vs[(dc * 32 + l31) * 32 + (((2 + h) ^ ((l31 >> 1) & 3)) << 3)];
      acc[dc] = __builtin_amdgcn_mfma_f32_32x32x16_bf16(vf1, pa1, acc[dc], 0, 0, 0);
    }
    __builtin_amdgcn_s_setprio(0);
    __syncthreads();  // drains staging vmcnt; all waves past V[pvb]
    scc = scn;
    sb = (sb + 1 == 3) ? 0 : sb + 1;
    qkb = (qkb + 1 == 3) ? 0 : qkb + 1;
    pvb = (pvb + 1 == 3) ? 0 : pvb + 1;
  }
  {
    auto rl = __builtin_amdgcn_permlane32_swap(__builtin_bit_cast(unsigned, lrun),
                                               __builtin_bit_cast(unsigned, lrun), false, false);
    lrun = asf(rl[0]) + asf(rl[1]);
  }
  const float inv = 1.0f / lrun;
  unsigned short* Op = ob + ((size_t)n * SS + qrow) * DD + dblk;
#pragma unroll
  for (int dc = 0; dc < 4; ++dc)
#pragma unroll
    for (int rg = 0; rg < 4; ++rg) {
      uint2 u;
      u.x = pk2(acc[dc][rg * 4 + 0] * inv, acc[dc][rg * 4 + 1] * inv);
      u.y = pk2(acc[dc][rg * 4 + 2] * inv, acc[dc][rg * 4 + 3] * inv);
      *(uint2*)(Op + dc * 32 + rg * 8 + h * 4) = u;
    }
}

// ---- fused proj + bias + residual, XCD-swizzled 1-D grid (512) ----
__global__ __launch_bounds__(256) void k_proj(const unsigned short* __restrict__ ob,
    const unsigned short* __restrict__ wpb, const float* __restrict__ bp,
    const float* __restrict__ x, float* __restrict__ out) {
  __shared__ __attribute__((aligned(16))) unsigned short As[128 * 32];
  __shared__ __attribute__((aligned(16))) unsigned short Bs[128 * 32];
  const int bid = blockIdx.x;
  const int xcd = bid & 7, idx = bid >> 3;          // idx 0..63
  const int n = xcd + ((idx >> 4) << 3);
  const int rem = idx & 15;
  const int s0 = (rem & 7) * 128;
  const int c0 = (rem >> 3) * 128;
  const int tid = threadIdx.x;
  const int lane = tid & 63, wid = tid >> 6;
  const int lo = lane & 15, hi = lane >> 4;
  const int wr = wid >> 1, wc = wid & 1;
  const unsigned short* On = ob + (size_t)n * SS * DD;
  f32x4 acc[4][4] = {};
  for (int k0 = 0; k0 < DD; k0 += 32) {
#pragma unroll
    for (int i = 0; i < 2; ++i) {
      const int seg = i * 256 + wid * 64 + lane;
      const int row = seg >> 2, c8 = seg & 3;
      GLOAD16(wpb + (size_t)(c0 + row) * DD + k0 + c8 * 8, As + (size_t)(i * 256 + wid * 64) * 8);
      GLOAD16(On + (size_t)(s0 + row) * DD + k0 + c8 * 8, Bs + (size_t)(i * 256 + wid * 64) * 8);
    }
    __syncthreads();
    s16x8 a[4], b[4];
#pragma unroll
    for (int mi = 0; mi < 4; ++mi)
      a[mi] = *(const s16x8*)&As[(wr * 64 + mi * 16 + lo) * 32 + hi * 8];
#pragma unroll
    for (int ni = 0; ni < 4; ++ni)
      b[ni] = *(const s16x8*)&Bs[(wc * 64 + ni * 16 + lo) * 32 + hi * 8];
#pragma unroll
    for (int mi = 0; mi < 4; ++mi)
#pragma unroll
      for (int ni = 0; ni < 4; ++ni)
        acc[mi][ni] = __builtin_amdgcn_mfma_f32_16x16x32_bf16(a[mi], b[ni], acc[mi][ni], 0, 0, 0);
    __syncthreads();
  }
#pragma unroll
  for (int mi = 0; mi < 4; ++mi) {
#pragma unroll
    for (int r = 0; r < 4; ++r) {
      const int c = c0 + wr * 64 + mi * 16 + hi * 4 + r;
      const float bpc = bp[c];
      const size_t base = ((size_t)n * CD + c) * SS;
#pragma unroll
      for (int ni = 0; ni < 4; ++ni) {
        const int s = s0 + wc * 64 + ni * 16 + lo;
        out[base + s] = acc[mi][ni][r] + bpc + x[base + s];
      }
    }
  }
}

extern "C" void kernel_launch(void* const* d_in, const int* in_sizes, int n_in,
                              void* d_out, int out_size, void* d_ws, size_t ws_size,
                              hipStream_t stream) {
  const float* x  = (const float*)d_in[0];
  const float* t  = (const float*)d_in[1];
  const float* Wt = (const float*)d_in[2];
  const float* bt = (const float*)d_in[3];
  const float* Wq = (const float*)d_in[4];
  const float* Wk = (const float*)d_in[5];
  const float* Wv = (const float*)d_in[6];
  const float* Wp = (const float*)d_in[7];
  const float* bp = (const float*)d_in[8];
  char* ws = (char*)d_ws;
  float* temb        = (float*)ws;                              // 32 KB
  unsigned short* wb = (unsigned short*)(ws + 32768);           // 512 KB (q,k,v,p)
  unsigned short* xb = (unsigned short*)(ws + 557056);          // 16 MB [n,s,c]
  unsigned char* qb8 = (unsigned char*)(ws + 17334272);         // 8 MB fp8 [n,s,d]
  unsigned char* kb8 = (unsigned char*)(ws + 34111488);         // 8 MB fp8 [n,s,d]
  unsigned short* vtb = (unsigned short*)(ws + 50888704);       // 16 MB bf16 [n,d,s]
  unsigned short* ob = (unsigned short*)(ws + 67665920);        // 16 MB bf16 [n,s,d]
  float* out = (float*)d_out;

  k_misc<<<1056, 256, 0, stream>>>(t, Wt, bt, temb, Wq, Wk, Wv, Wp, wb);
  k_addT<<<dim3(8, 32, 32), 256, 0, stream>>>(x, temb, xb);
  k_qkv<<<1536, 256, 0, stream>>>(xb, wb, qb8, kb8, vtb);
  k_attn<<<512, 256, 0, stream>>>(qb8, kb8, vtb, ob);
  k_proj<<<512, 256, 0, stream>>>(ob, wb + 196608, bp, x, out);
}